// Round 13
// baseline (346.469 us; speedup 1.0000x reference)
//
#include <hip/hip_runtime.h>
#include <hip/hip_bf16.h>

// MambaLM: B=2,K=4,T=1024,V=1024, d_model=512, d_inner=1024, N=16, dt_rank=32, L=2
// R21 = R20 + scan2 merged into scan3 (scan23_k): each block computes its own
// chunk-prefix h0 by folding pA/U over c2<c (identical FMA order -> bit-identical),
// reading the L2-resident pA/U directly. Removes: scan2 kernel (128-blk,
// latency-bound), hst write+read (33.6 MB), 2 dispatch boundaries. 14 -> 12
// dispatches. All other kernels byte-identical to R20.

#define B_SZ 2
#define K_CB 4
#define T_SZ 1024
#define V_SZ 1024
#define DM 512
#define DI 1024
#define NS 16
#define DTR 32
#define NCHUNK 64
#define TCHUNK 16

typedef unsigned short u16;
typedef long long ll;
using short8 = __attribute__((ext_vector_type(8))) short;
using f32x4  = __attribute__((ext_vector_type(4))) float;

__device__ __forceinline__ float bf2f(u16 u) {
    union { unsigned int i; float f; } v; v.i = ((unsigned int)u) << 16; return v.f;
}
__device__ __forceinline__ u16 f2bf(float f) {
    union { float f; unsigned int i; } v; v.f = f;
    unsigned int x = v.i;
    return (u16)((x + 0x7fffu + ((x >> 16) & 1u)) >> 16);
}
__device__ __forceinline__ float siluf(float x) { return x / (1.f + __expf(-x)); }
__device__ __forceinline__ float softplusf(float x) { return (x > 20.f) ? x : log1pf(__expf(x)); }
__device__ __forceinline__ float sumsq8(uint4 v) {
    const u16* e = (const u16*)&v;
    float s = 0.f;
#pragma unroll
    for (int t = 0; t < 8; t++) { float f = bf2f(e[t]); s = fmaf(f, f, s); }
    return s;
}

// ---------------- mega setup: weight cvt (3264 blk, nw folded into l=1 in_w)
//                  + head transpose (512 blk) + embed+rmsnorm (2048 blk) ----------------
__global__ __launch_bounds__(256) void mega0_k(const float* __restrict__ in_w,
                                               const float* __restrict__ xp_w,
                                               const float* __restrict__ dtp_w,
                                               const float* __restrict__ out_w,
                                               u16* __restrict__ w_in, u16* __restrict__ w_xp,
                                               u16* __restrict__ w_dt, u16* __restrict__ w_out,
                                               const float* __restrict__ head_w,
                                               u16* __restrict__ w_hd,
                                               const int* __restrict__ codes,
                                               const float* __restrict__ ew,
                                               const float* __restrict__ nw,
                                               float* __restrict__ x,
                                               u16* __restrict__ xn) {
    __shared__ float tile[64][65];
    int bid = blockIdx.x;
    int tid = threadIdx.x;
    if (bid < 3264) {
        // flat f32->bf16: in_w (2097152) | xp_w (131072) | dtp_w (65536) | out_w (1048576)
        int i0 = (bid * 256 + tid) << 2;
        int i = i0;
        const float* s; u16* d;
        bool in_w_l1 = false;
        if (i < 2097152) {
            s = in_w + i; d = w_in + i;
            in_w_l1 = (i >= 1048576);     // l=1 half: fold nw (f32, pre-rounding)
        } else {
            i -= 2097152;
            if (i < 131072) { s = xp_w + i; d = w_xp + i; }
            else {
                i -= 131072;
                if (i < 65536) { s = dtp_w + i; d = w_dt + i; }
                else { i -= 65536; s = out_w + i; d = w_out + i; }
            }
        }
        float4 v = *(const float4*)s;
        if (in_w_l1) {
            int k = i0 & 511;               // DM=512 innermost
            const float* nr = nw + DM;      // l=1 norm row
            v.x *= nr[k]; v.y *= nr[k + 1]; v.z *= nr[k + 2]; v.w *= nr[k + 3];
        }
        ushort4 o; o.x = f2bf(v.x); o.y = f2bf(v.y); o.z = f2bf(v.z); o.w = f2bf(v.w);
        *(ushort4*)d = o;
    } else if (bid < 3776) {
        // head transpose: w[4][512][1024] f32 -> wt[4][1024][512] bf16
        int idx = bid - 3264;
        int z = idx >> 7, rest = idx & 127;
        int d0 = (rest >> 4) << 6, v0 = (rest & 15) << 6;
        int col = tid & 63, rbase = tid >> 6;
#pragma unroll
        for (int i = 0; i < 16; i++) {
            int row = (i << 2) + rbase;
            tile[row][col] = head_w[(ll)z * (DM * V_SZ) + (ll)(d0 + row) * V_SZ + v0 + col];
        }
        __syncthreads();
#pragma unroll
        for (int i = 0; i < 16; i++) {
            int vrow = (i << 2) + rbase;
            w_hd[(ll)z * (V_SZ * DM) + (ll)(v0 + vrow) * DM + d0 + col] = f2bf(tile[col][vrow]);
        }
    } else {
        // embedding + rmsnorm (layer-0 input)
        int row = bid - 3776;  // b*1024 + t
        int b = row >> 10, t = row & 1023;
        float a0 = 0.f, a1 = 0.f;
#pragma unroll
        for (int k = 0; k < K_CB; k++) {
            int c = codes[b * (K_CB * T_SZ) + k * T_SZ + t];
            a0 += ew[((ll)k * V_SZ + c) * DM + tid];
            a1 += ew[((ll)k * V_SZ + c) * DM + tid + 256];
        }
        x[(ll)row * DM + tid]       = a0;
        x[(ll)row * DM + tid + 256] = a1;
        float ss = a0 * a0 + a1 * a1;
#pragma unroll
        for (int off = 32; off > 0; off >>= 1) ss += __shfl_down(ss, off, 64);
        float* red = &tile[0][0];
        if ((tid & 63) == 0) red[tid >> 6] = ss;
        __syncthreads();
        float tot = red[0] + red[1] + red[2] + red[3];
        float scale = rsqrtf(tot * (1.0f / DM) + 1e-6f);
        xn[(ll)row * DM + tid]       = f2bf(a0 * scale * nw[tid]);
        xn[(ll)row * DM + tid + 256] = f2bf(a1 * scale * nw[tid + 256]);
    }
}

// ---------------- 128x128 MFMA GEMM, reg-prefetch + dual-LDS pipeline ----------------
// C[M,N] = A[M,K](bf16) * W[N,K](bf16)^T.  4 waves 2x2 -> each wave 64x64 = 4x4 mfma.
// EP0: bf16 store Cb (in_proj l=0).  EP4: head f32 scatter (z=n>>10, v=n&1023).
template <int EP>
__global__ __launch_bounds__(256) void mgemm2_k(const u16* __restrict__ A, int lda,
                                                const u16* __restrict__ W,
                                                float* __restrict__ C,
                                                u16* __restrict__ Cb, int ldcb, int K) {
    __shared__ u16 As[2][4096];   // [128][32] each
    __shared__ u16 Bs[2][4096];
    int tid = threadIdx.x;
    int wave = tid >> 6, lane = tid & 63;
    int q = lane >> 4, r = lane & 15;
    int m0 = blockIdx.y << 7, n0 = blockIdx.x << 7;
    int wm = (wave >> 1) << 6, wn = (wave & 1) << 6;
    int srow = tid >> 1, soff = (tid & 1) << 4;     // row 0..127, u16-offset 0/16
    const u16* Ap = A + (ll)(m0 + srow) * lda + soff;
    const u16* Wp = W + (ll)(n0 + srow) * K + soff;
    int sidx = (srow << 5) + soff;
    f32x4 acc[4][4];
#pragma unroll
    for (int i = 0; i < 4; i++)
#pragma unroll
        for (int j = 0; j < 4; j++) acc[i][j] = (f32x4){0.f, 0.f, 0.f, 0.f};

    uint4 ra0 = *(const uint4*)Ap,       ra1 = *(const uint4*)(Ap + 8);
    uint4 rb0 = *(const uint4*)Wp,       rb1 = *(const uint4*)(Wp + 8);
    *(uint4*)&As[0][sidx] = ra0; *(uint4*)&As[0][sidx + 8] = ra1;
    *(uint4*)&Bs[0][sidx] = rb0; *(uint4*)&Bs[0][sidx + 8] = rb1;
    __syncthreads();

    int p = 0;
    for (int k0 = 0; k0 < K; k0 += 32) {
        bool pf = (k0 + 32) < K;
        if (pf) {
            ra0 = *(const uint4*)(Ap + k0 + 32); ra1 = *(const uint4*)(Ap + k0 + 40);
            rb0 = *(const uint4*)(Wp + k0 + 32); rb1 = *(const uint4*)(Wp + k0 + 40);
        }
        short8 af[4], bfr[4];
#pragma unroll
        for (int i = 0; i < 4; i++) af[i]  = *(const short8*)&As[p][((wm + (i << 4) + r) << 5) + (q << 3)];
#pragma unroll
        for (int j = 0; j < 4; j++) bfr[j] = *(const short8*)&Bs[p][((wn + (j << 4) + r) << 5) + (q << 3)];
#pragma unroll
        for (int i = 0; i < 4; i++)
#pragma unroll
            for (int j = 0; j < 4; j++)
                acc[i][j] = __builtin_amdgcn_mfma_f32_16x16x32_bf16(af[i], bfr[j], acc[i][j], 0, 0, 0);
        if (pf) {
            *(uint4*)&As[p ^ 1][sidx] = ra0; *(uint4*)&As[p ^ 1][sidx + 8] = ra1;
            *(uint4*)&Bs[p ^ 1][sidx] = rb0; *(uint4*)&Bs[p ^ 1][sidx + 8] = rb1;
        }
        __syncthreads();
        p ^= 1;
    }

#pragma unroll
    for (int i = 0; i < 4; i++)
#pragma unroll
        for (int j = 0; j < 4; j++)
#pragma unroll
            for (int g = 0; g < 4; g++) {
                int m = m0 + wm + (i << 4) + (q << 2) + g;
                int n = n0 + wn + (j << 4) + r;
                float v = acc[i][j][g];
                if (EP == 0) {
                    Cb[(ll)m * ldcb + n] = f2bf(v);
                } else {
                    int z = n >> 10, vv = n & 1023;
                    int b = m >> 10, t = m & 1023;
                    C[((ll)(b * K_CB + z) * T_SZ + t) * V_SZ + vv] = v;
                }
            }
}

// ---------------- in_proj(l=1) GEMM with fused rmsnorm (standalone copy) ----------------
// A = x_bf (raw residual, bf16). W has nw pre-folded. Per-row sumsq computed during
// A-staging (each stager covers 256 of the row's 512 elems; pair-combine in LDS);
// epilogue scales acc by rsqrt(sumsq/512 + eps). bf16 store to Cb.
__global__ __launch_bounds__(256) void inprojrms_k(const u16* __restrict__ A, int lda,
                                                   const u16* __restrict__ W,
                                                   u16* __restrict__ Cb, int ldcb, int K) {
    __shared__ u16 As[2][4096];   // [128][32] each
    __shared__ u16 Bs[2][4096];
    __shared__ float rs_lds[128][2];
    int tid = threadIdx.x;
    int wave = tid >> 6, lane = tid & 63;
    int q = lane >> 4, r = lane & 15;
    int m0 = blockIdx.y << 7, n0 = blockIdx.x << 7;
    int wm = (wave >> 1) << 6, wn = (wave & 1) << 6;
    int srow = tid >> 1, soff = (tid & 1) << 4;     // row 0..127, u16-offset 0/16
    const u16* Ap = A + (ll)(m0 + srow) * lda + soff;
    const u16* Wp = W + (ll)(n0 + srow) * K + soff;
    int sidx = (srow << 5) + soff;
    f32x4 acc[4][4];
#pragma unroll
    for (int i = 0; i < 4; i++)
#pragma unroll
        for (int j = 0; j < 4; j++) acc[i][j] = (f32x4){0.f, 0.f, 0.f, 0.f};

    float ss = 0.f;
    uint4 ra0 = *(const uint4*)Ap,       ra1 = *(const uint4*)(Ap + 8);
    uint4 rb0 = *(const uint4*)Wp,       rb1 = *(const uint4*)(Wp + 8);
    ss += sumsq8(ra0); ss += sumsq8(ra1);
    *(uint4*)&As[0][sidx] = ra0; *(uint4*)&As[0][sidx + 8] = ra1;
    *(uint4*)&Bs[0][sidx] = rb0; *(uint4*)&Bs[0][sidx + 8] = rb1;
    __syncthreads();

    int p = 0;
    for (int k0 = 0; k0 < K; k0 += 32) {
        bool pf = (k0 + 32) < K;
        if (pf) {
            ra0 = *(const uint4*)(Ap + k0 + 32); ra1 = *(const uint4*)(Ap + k0 + 40);
            rb0 = *(const uint4*)(Wp + k0 + 32); rb1 = *(const uint4*)(Wp + k0 + 40);
            ss += sumsq8(ra0); ss += sumsq8(ra1);
        }
        short8 af[4], bfr[4];
#pragma unroll
        for (int i = 0; i < 4; i++) af[i]  = *(const short8*)&As[p][((wm + (i << 4) + r) << 5) + (q << 3)];
#pragma unroll
        for (int j = 0; j < 4; j++) bfr[j] = *(const short8*)&Bs[p][((wn + (j << 4) + r) << 5) + (q << 3)];
#pragma unroll
        for (int i = 0; i < 4; i++)
#pragma unroll
            for (int j = 0; j < 4; j++)
                acc[i][j] = __builtin_amdgcn_mfma_f32_16x16x32_bf16(af[i], bfr[j], acc[i][j], 0, 0, 0);
        if (pf) {
            *(uint4*)&As[p ^ 1][sidx] = ra0; *(uint4*)&As[p ^ 1][sidx + 8] = ra1;
            *(uint4*)&Bs[p ^ 1][sidx] = rb0; *(uint4*)&Bs[p ^ 1][sidx + 8] = rb1;
        }
        __syncthreads();
        p ^= 1;
    }

    // pair-combine per-row sumsq
    rs_lds[srow][tid & 1] = ss;
    __syncthreads();

#pragma unroll
    for (int i = 0; i < 4; i++)
#pragma unroll
        for (int g = 0; g < 4; g++) {
            int mm = wm + (i << 4) + (q << 2) + g;
            float scale = rsqrtf((rs_lds[mm][0] + rs_lds[mm][1]) * (1.0f / DM) + 1e-6f);
            int m = m0 + mm;
#pragma unroll
            for (int j = 0; j < 4; j++) {
                int n = n0 + wn + (j << 4) + r;
                Cb[(ll)m * ldcb + n] = f2bf(acc[i][j][g] * scale);
            }
        }
}

// ---------------- 64x64 MFMA GEMM, reg-prefetch + dual-LDS pipeline ----------------
// EP3: C += acc, Cb = bf16(C) (out_proj).
template <int EP>
__global__ __launch_bounds__(256) void mgemm_k(const u16* __restrict__ A, int lda,
                                               const u16* __restrict__ W,
                                               float* __restrict__ C, int ldc, int K,
                                               const float* __restrict__ bias,
                                               u16* __restrict__ Cb, int ldcb) {
    __shared__ u16 As[2][2048];   // [64][32] each
    __shared__ u16 Bs[2][2048];
    int tid = threadIdx.x;
    int m0 = blockIdx.y << 6, n0 = blockIdx.x << 6;
    int lane = tid & 63, wave = tid >> 6;
    int q = lane >> 4, r = lane & 15;
    int wm = (wave >> 1) << 5, wn = (wave & 1) << 5;
    int srow = tid >> 2, soff = (tid & 3) << 3;     // row 0..63, u16-offset 0/8/16/24
    const u16* Ap = A + (ll)(m0 + srow) * lda + soff;
    const u16* Wp = W + (ll)(n0 + srow) * K + soff;
    int sidx = (srow << 5) + soff;
    f32x4 acc[2][2];
#pragma unroll
    for (int i = 0; i < 2; i++)
#pragma unroll
        for (int j = 0; j < 2; j++) acc[i][j] = (f32x4){0.f, 0.f, 0.f, 0.f};

    uint4 ra = *(const uint4*)Ap;
    uint4 rb = *(const uint4*)Wp;
    *(uint4*)&As[0][sidx] = ra;
    *(uint4*)&Bs[0][sidx] = rb;
    __syncthreads();

    int p = 0;
    for (int k0 = 0; k0 < K; k0 += 32) {
        bool pf = (k0 + 32) < K;
        if (pf) {
            ra = *(const uint4*)(Ap + k0 + 32);
            rb = *(const uint4*)(Wp + k0 + 32);
        }
        short8 af[2], bfr[2];
#pragma unroll
        for (int i = 0; i < 2; i++) af[i]  = *(const short8*)&As[p][((wm + (i << 4) + r) << 5) + (q << 3)];
#pragma unroll
        for (int j = 0; j < 2; j++) bfr[j] = *(const short8*)&Bs[p][((wn + (j << 4) + r) << 5) + (q << 3)];
#pragma unroll
        for (int i = 0; i < 2; i++)
#pragma unroll
            for (int j = 0; j < 2; j++)
                acc[i][j] = __builtin_amdgcn_mfma_f32_16x16x32_bf16(af[i], bfr[j], acc[i][j], 0, 0, 0);
        if (pf) {
            *(uint4*)&As[p ^ 1][sidx] = ra;
            *(uint4*)&Bs[p ^ 1][sidx] = rb;
        }
        __syncthreads();
        p ^= 1;
    }

#pragma unroll
    for (int i = 0; i < 2; i++)
#pragma unroll
        for (int j = 0; j < 2; j++)
#pragma unroll
            for (int g = 0; g < 4; g++) {
                int m = m0 + wm + (i << 4) + (q << 2) + g;
                int n = n0 + wn + (j << 4) + r;
                float v = acc[i][j][g];
                float nv = C[(ll)m * ldc + n] + v;
                C[(ll)m * ldc + n] = nv;
                Cb[(ll)m * ldcb + n] = f2bf(nv);
            }
}

// ---------------- fused causal dwconv(4)+silu + x_proj GEMM ----------------
// grid 128 = B * 64 row-groups; block owns 16 t-rows.
__global__ __launch_bounds__(256) void convxp_k(const u16* __restrict__ xzb,
                                                const float* __restrict__ cw,
                                                const float* __restrict__ cb,
                                                const u16* __restrict__ W,
                                                float* __restrict__ xc,
                                                float* __restrict__ xdbl,
                                                u16* __restrict__ xdbl_bf) {
    __shared__ u16 xcs[16][1032];   // bf16 xc tile, padded stride (16B pad)
    __shared__ u16 Bs[2][2048];     // [64][32] dbuf for W
    int blk = blockIdx.x, tid = threadIdx.x;
    int b = blk >> 6, tg = blk & 63;
    int t0 = tg << 4;
    ll ro0 = (ll)b * T_SZ + t0;
    int c0 = tid << 2;
    // conv weights + bias
    float4 a = *(const float4*)&cb[c0];
    float4 cwv[4];
#pragma unroll
    for (int e = 0; e < 4; e++) cwv[e] = *(const float4*)&cw[(c0 + e) << 2];
    // input rows t0-3 .. t0+15 for this thread's 4 channels
    ushort4 v[19];
#pragma unroll
    for (int i = 0; i < 19; i++) {
        int t = t0 - 3 + i;
        if (t >= 0) v[i] = *(const ushort4*)&xzb[((ll)(b * T_SZ + t)) * (2 * DI) + c0];
        else        v[i] = (ushort4){0, 0, 0, 0};
    }
#pragma unroll
    for (int tr = 0; tr < 16; tr++) {
        float acc0 = a.x, acc1 = a.y, acc2 = a.z, acc3 = a.w;
#pragma unroll
        for (int j = 0; j < 4; j++) {
            ushort4 vv = v[tr + j];
            acc0 = fmaf(bf2f(vv.x), ((const float*)&cwv[0])[j], acc0);
            acc1 = fmaf(bf2f(vv.y), ((const float*)&cwv[1])[j], acc1);
            acc2 = fmaf(bf2f(vv.z), ((const float*)&cwv[2])[j], acc2);
            acc3 = fmaf(bf2f(vv.w), ((const float*)&cwv[3])[j], acc3);
        }
        float4 s; ushort4 sb;
        s.x = siluf(acc0); s.y = siluf(acc1); s.z = siluf(acc2); s.w = siluf(acc3);
        sb.x = f2bf(s.x); sb.y = f2bf(s.y); sb.z = f2bf(s.z); sb.w = f2bf(s.w);
        *(float4*)&xc[(ro0 + tr) * DI + c0] = s;
        *(ushort4*)&xcs[tr][c0] = sb;
    }
    __syncthreads();

    // Phase 2: MFMA x_dbl = xcs(16x1024) @ W(64x1024)^T
    int lane = tid & 63, wave = tid >> 6;
    int q = lane >> 4, r = lane & 15;
    int srow = tid >> 2, soff = (tid & 3) << 3;
    f32x4 acc = (f32x4){0.f, 0.f, 0.f, 0.f};
    uint4 rb = *(const uint4*)(W + (ll)srow * DI + soff);
    *(uint4*)&Bs[0][(srow << 5) + soff] = rb;
    __syncthreads();
    int p = 0;
    for (int k0 = 0; k0 < DI; k0 += 32) {
        bool pf = (k0 + 32) < DI;
        if (pf) rb = *(const uint4*)(W + (ll)srow * DI + k0 + 32 + soff);
        short8 af  = *(const short8*)&xcs[r][k0 + (q << 3)];
        short8 bfr = *(const short8*)&Bs[p][(((wave << 4) + r) << 5) + (q << 3)];
        acc = __builtin_amdgcn_mfma_f32_16x16x32_bf16(af, bfr, acc, 0, 0, 0);
        if (pf) *(uint4*)&Bs[p ^ 1][(srow << 5) + soff] = rb;
        __syncthreads();
        p ^= 1;
    }
    // C/D layout: row = q*4+g (t within tile), col = r; wave's col base = wave*16
#pragma unroll
    for (int g = 0; g < 4; g++) {
        int tr = (q << 2) + g;
        int n = (wave << 4) + r;
        float vv = acc[g];
        xdbl[(ro0 + tr) * 64 + n]    = vv;
        xdbl_bf[(ro0 + tr) * 64 + n] = f2bf(vv);
    }
}

// ---------------- fused dt_proj GEMM + scan pass 1 ----------------
// grid dim3(16,32) = 512 blocks; tile 64(t) x 64(d).
// xc tile staged to LDS (loads issued at kernel top); scan loop LDS-only.
// pA/U: [b][c][n][d] dense layout.
__global__ __launch_bounds__(256) void dtscan1_k(const u16* __restrict__ A,
                                                 const u16* __restrict__ W,
                                                 const float* __restrict__ bias,
                                                 const float* __restrict__ xc,
                                                 const float* __restrict__ xdbl,
                                                 const float* __restrict__ A_log,
                                                 float* __restrict__ dtb,
                                                 float* __restrict__ pA,
                                                 float* __restrict__ U) {
    __shared__ u16 As[2048];        // [64][32]
    __shared__ u16 Bs[2048];
    __shared__ float dts[64][65];   // padded
    __shared__ float BCs[64][16];   // B part of x_dbl for the block's 64 rows
    __shared__ float xcs[64][65];   // xc tile (padded: writes 2-way, reads free)
    int tid = threadIdx.x;
    int m0 = blockIdx.y << 6, n0 = blockIdx.x << 6;
    int lane = tid & 63, wave = tid >> 6;
    int q = lane >> 4, r = lane & 15;
    int wm = (wave >> 1) << 5, wn = (wave & 1) << 5;

    // issue xc tile loads FIRST: thread -> row tid>>2, col chunk (tid&3)*16
    int xr = tid >> 2, xcb = (tid & 3) << 4;
    const float* xp = &xc[(ll)(m0 + xr) * DI + n0 + xcb];
    float4 xv0 = *(const float4*)(xp);
    float4 xv1 = *(const float4*)(xp + 4);
    float4 xv2 = *(const float4*)(xp + 8);
    float4 xv3 = *(const float4*)(xp + 12);

    {   // stage A (xdbl_bf rows m0.., k=0..31) and B (w_dt rows n0.., k=0..31)
        int srow = tid >> 2, soff = (tid & 3) << 3;
        *(uint4*)&As[(srow << 5) + soff] = *(const uint4*)(A + (ll)(m0 + srow) * 64 + soff);
        *(uint4*)&Bs[(srow << 5) + soff] = *(const uint4*)(W + (ll)(n0 + srow) * DTR + soff);
        // stage B-coefficients for scan: xdbl[row][32..47], 64 rows x 16 f32
        int rr = tid >> 2, cc = (tid & 3) << 2;
        *(float4*)&BCs[rr][cc] = *(const float4*)&xdbl[(ll)(m0 + rr) * 64 + DTR + cc];
    }
    // per-thread scan constants
    int sd = lane;             // d offset within tile (scan mapping)
    int sc = wave;             // chunk 0..3 within tile
    int dg = n0 + sd;
    float Av[NS];
#pragma unroll
    for (int n4 = 0; n4 < 4; n4++) {
        float4 alv = *(const float4*)&A_log[dg * NS + (n4 << 2)];
        Av[(n4 << 2) + 0] = -__expf(alv.x); Av[(n4 << 2) + 1] = -__expf(alv.y);
        Av[(n4 << 2) + 2] = -__expf(alv.z); Av[(n4 << 2) + 3] = -__expf(alv.w);
    }
    // write xc tile to LDS (loads have had Av-exp time to land)
    *(float4*)&xcs[xr][xcb]      = xv0;
    *(float4*)&xcs[xr][xcb + 4]  = xv1;
    *(float4*)&xcs[xr][xcb + 8]  = xv2;
    *(float4*)&xcs[xr][xcb + 12] = xv3;
    __syncthreads();

    // GEMM: one K=32 step
    f32x4 acc[2][2];
#pragma unroll
    for (int i = 0; i < 2; i++)
#pragma unroll
        for (int j = 0; j < 2; j++) acc[i][j] = (f32x4){0.f, 0.f, 0.f, 0.f};
    short8 af[2], bfr[2];
#pragma unroll
    for (int i = 0; i < 2; i++) af[i]  = *(const short8*)&As[((wm + (i << 4) + r) << 5) + (q << 3)];
#pragma unroll
    for (int j = 0; j < 2; j++) bfr[j] = *(const short8*)&Bs[((wn + (j << 4) + r) << 5) + (q << 3)];
#pragma unroll
    for (int i = 0; i < 2; i++)
#pragma unroll
        for (int j = 0; j < 2; j++)
            acc[i][j] = __builtin_amdgcn_mfma_f32_16x16x32_bf16(af[i], bfr[j], acc[i][j], 0, 0, 0);

    // epilogue: softplus(+bias) -> dtb global + dts LDS
#pragma unroll
    for (int i = 0; i < 2; i++)
#pragma unroll
        for (int j = 0; j < 2; j++)
#pragma unroll
            for (int g = 0; g < 4; g++) {
                int mm = wm + (i << 4) + (q << 2) + g;
                int nn = wn + (j << 4) + r;
                float dtl = softplusf(acc[i][j][g] + bias[n0 + nn]);
                dtb[(ll)(m0 + mm) * DI + (n0 + nn)] = dtl;
                dts[mm][nn] = dtl;
            }
    __syncthreads();

    // scan pass 1: thread (sc, sd) runs chunk c over its 16 steps — LDS-only loop
    int b = m0 >> 10;
    int c = ((m0 & 1023) >> 4) + sc;
    int tl0 = sc << 4;
    float p[NS], u[NS];
#pragma unroll
    for (int n = 0; n < NS; n++) { p[n] = 1.f; u[n] = 0.f; }
#pragma unroll
    for (int s = 0; s < TCHUNK; s++) {
        int tl = tl0 + s;
        float dtv = dts[tl][sd];
        float xl = xcs[tl][sd];
        float dx = dtv * xl;
#pragma unroll
        for (int n = 0; n < NS; n++) {
            float aa = __expf(dtv * Av[n]);
            p[n] *= aa;
            u[n] = fmaf(aa, u[n], dx * BCs[tl][n]);
        }
    }
    // store: [b][c][n][d] layout -> lane-consecutive d = dense 256B per instr
    ll o = ((ll)b * NCHUNK + c) * (NS * DI) + dg;
#pragma unroll
    for (int n = 0; n < NS; n++) { pA[o + n * DI] = p[n]; U[o + n * DI] = u[n]; }
}

// ---------------- merged scan pass 2+3 ----------------
// grid 512 = (b, chunk c, dblk).  Each block computes its own chunk-prefix
// h0 = fold_{c2<c}(pA*h + U)  (identical FMA order to the old scan2 -> bit-identical),
// reading L2-resident pA/U directly.  Then replay chunk c with D_skip + silu(z)
// gate; bf16 y out.  hst buffer and scan2 dispatch eliminated.
__global__ __launch_bounds__(256) void scan23_k(const float* __restrict__ dt,
                                                const float* __restrict__ xc,
                                                const float* __restrict__ xdbl,
                                                const u16* __restrict__ xzb,
                                                const float* __restrict__ A_log,
                                                const float* __restrict__ Dk,
                                                const float* __restrict__ pA,
                                                const float* __restrict__ U,
                                                u16* __restrict__ y) {
    int blk = blockIdx.x;
    int dblk = blk & 3;
    int c = (blk >> 2) & (NCHUNK - 1);
    int b = blk >> 8;
    int d = dblk * 256 + threadIdx.x;
    int t0 = c * TCHUNK;
    __shared__ float BC[TCHUNK][32];
    if (threadIdx.x < TCHUNK * 8) {
        int rr = threadIdx.x >> 3, cc = (threadIdx.x & 7) << 2;
        *(float4*)&BC[rr][cc] = *(const float4*)&xdbl[((ll)(b * T_SZ + t0 + rr)) * 64 + DTR + cc];
    }
    float Av[NS];
#pragma unroll
    for (int n4 = 0; n4 < 4; n4++) {
        float4 alv = *(const float4*)&A_log[d * NS + (n4 << 2)];
        Av[(n4 << 2) + 0] = -__expf(alv.x); Av[(n4 << 2) + 1] = -__expf(alv.y);
        Av[(n4 << 2) + 2] = -__expf(alv.z); Av[(n4 << 2) + 3] = -__expf(alv.w);
    }
    // chunk-prefix combine: h = fold over chunks c2 < c (ascending)
    float h[NS];
#pragma unroll
    for (int n = 0; n < NS; n++) h[n] = 0.f;
    ll bb = (ll)b * NCHUNK * (NS * DI) + d;
    for (int c2 = 0; c2 < c; c2++) {
        ll o = bb + (ll)c2 * (NS * DI);
#pragma unroll
        for (int n = 0; n < NS; n++) {
            float pa = pA[o + n * DI];
            float uu = U[o + n * DI];
            h[n] = fmaf(pa, h[n], uu);
        }
    }
    float Dv = Dk[d];
    __syncthreads();
#pragma unroll
    for (int s = 0; s < TCHUNK; s++) {
        ll ro = (ll)(b * T_SZ + t0 + s);
        float dtv = dt[ro * DI + d];
        float xv = xc[ro * DI + d];
        float dx = dtv * xv;
        float acc = 0.f;
#pragma unroll
        for (int n = 0; n < NS; n++) {
            float aa = __expf(dtv * Av[n]);
            h[n] = fmaf(aa, h[n], dx * BC[s][n]);
            acc = fmaf(h[n], BC[s][16 + n], acc);
        }
        float zv = bf2f(xzb[ro * (2 * DI) + DI + d]);
        y[ro * DI + d] = f2bf((acc + xv * Dv) * siluf(zv));
    }
}

extern "C" void kernel_launch(void* const* d_in, const int* in_sizes, int n_in,
                              void* d_out, int out_size, void* d_ws, size_t ws_size,
                              hipStream_t stream) {
    const int*   codes   = (const int*)d_in[0];
    const float* embed_w = (const float*)d_in[1];
    const float* norm_w  = (const float*)d_in[2];
    const float* in_w    = (const float*)d_in[3];
    const float* conv_w  = (const float*)d_in[4];
    const float* conv_b  = (const float*)d_in[5];
    const float* xp_w    = (const float*)d_in[6];
    const float* dtp_w   = (const float*)d_in[7];
    const float* dtp_b   = (const float*)d_in[8];
    const float* A_log   = (const float*)d_in[9];
    const float* D_skip  = (const float*)d_in[10];
    const float* out_w   = (const float*)d_in[11];
    const float* head_w  = (const float*)d_in[12];
    float* out = (float*)d_out;

    float* ws = (float*)d_ws;
    float* x    = ws;                  // 1,048,576 f32
    float* xc   = x + 1048576;         // 2,097,152
    float* dtb  = xc + 2097152;        // 2,097,152
    float* xdbl = dtb + 2097152;       // 131,072
    float* pA   = xdbl + 131072;       // 2,097,152
    float* Uh   = pA + 2097152;        // 2,097,152 (U)

    u16* us       = (u16*)(Uh + 2097152);
    u16* xz_bf    = us;                 // 4,194,304
    u16* xbf      = xz_bf + 4194304;    // 2,097,152 (x_bf: bf16 of residual x)
    u16* ybxn_bf  = xbf + 2097152;      // 2,097,152 (y_bf full; xn_bf shares first 1M)
    u16* xdbl_bf  = ybxn_bf + 2097152;  // 131,072
    u16* w_in_bf  = xdbl_bf + 131072;   // 2,097,152
    u16* w_xp_bf  = w_in_bf + 2097152;  // 131,072
    u16* w_dt_bf  = w_xp_bf + 131072;   // 65,536
    u16* w_out_bf = w_dt_bf + 65536;    // 1,048,576
    u16* w_hd_bf  = w_out_bf + 1048576; // 2,097,152 ([4096][512])

    u16* xn_bf = ybxn_bf;
    u16* y_bf  = ybxn_bf;
    u16* x_bf  = xbf;

    // setup: weight conversions (nw folded into l=1 in_proj W) + head transpose
    // + embed/rmsnorm, one dispatch
    mega0_k<<<5824, 256, 0, stream>>>(in_w, xp_w, dtp_w, out_w,
                                      w_in_bf, w_xp_bf, w_dt_bf, w_out_bf,
                                      head_w, w_hd_bf, codes, embed_w, norm_w, x, xn_bf);

    for (int l = 0; l < 2; l++) {
        const float* al = A_log + l * DI * NS;
        // xz = xn @ in_w^T : (2048 x 2048), K=512 -> bf16.  128x128 tiles, 256 blocks
        if (l == 0)
            mgemm2_k<0><<<dim3(16, 16), 256, 0, stream>>>(xn_bf, DM, w_in_bf,
                                                          nullptr, xz_bf, 2 * DI, DM);
        else
            inprojrms_k<<<dim3(16, 16), 256, 0, stream>>>(x_bf, DM, w_in_bf + 1048576,
                                                          xz_bf, 2 * DI, DM);
        // fused conv + x_proj: 128 blocks
        convxp_k<<<128, 256, 0, stream>>>(xz_bf, conv_w + l * DI * 4, conv_b + l * DI,
                                          w_xp_bf + l * 65536, xc, xdbl, xdbl_bf);
        // fused dt_proj + scan pass 1: 512 blocks
        dtscan1_k<<<dim3(16, 32), 256, 0, stream>>>(xdbl_bf, w_dt_bf + l * 32768,
                                                    dtp_b + l * DI, xc, xdbl, al,
                                                    dtb, pA, Uh);
        // merged scan pass 2+3: 512 blocks (per-block chunk-prefix combine)
        scan23_k<<<512, 256, 0, stream>>>(dtb, xc, xdbl, xz_bf, al, D_skip + l * DI,
                                          pA, Uh, y_bf);
        // x += y @ out_w^T : (2048 x 512), K=1024; also x_bf = bf16(x)
        mgemm_k<3><<<dim3(8, 32), 256, 0, stream>>>(y_bf, DI, w_out_bf + l * 524288,
                                                    x, DM, DI, nullptr, x_bf, DM);
    }

    // head: single GEMM M=2048 x N=4096 x K=512, 128x128 tiles, 512 blocks = 2 blk/CU
    mgemm2_k<4><<<dim3(32, 16), 256, 0, stream>>>(x_bf, DM, w_hd_bf, out, nullptr, 0, DM);
}

// Round 14
// 281.199 us; speedup vs baseline: 1.2321x; 1.2321x over previous
//
#include <hip/hip_runtime.h>
#include <hip/hip_bf16.h>

// MambaLM: B=2,K=4,T=1024,V=1024, d_model=512, d_inner=1024, N=16, dt_rank=32, L=2
// R22 = R17 verbatim — the best harness-verified variant (283.2 us).
// R21's scan2->scan23 merge reverted: the redundant chunk-prefix fold is a serial
// dependent chain (avg 32x16 FMAs fed by strided L2 loads, no latency hiding) ->
// +61 us. R18/R20-style rmsnorm folds: null or negative. Final configuration:
// 15 dispatches: mega0 | per layer {rmsnorm(l=1 only), in_proj 128x128, conv+x_proj
// fused, dt_proj+scan1 fused, scan2, scan3, out_proj} | head GEMM.
// pA/U/hst in [b][c][n][d] layout (dense lane-consecutive stores).

#define B_SZ 2
#define K_CB 4
#define T_SZ 1024
#define V_SZ 1024
#define DM 512
#define DI 1024
#define NS 16
#define DTR 32
#define NCHUNK 64
#define TCHUNK 16

typedef unsigned short u16;
typedef long long ll;
using short8 = __attribute__((ext_vector_type(8))) short;
using f32x4  = __attribute__((ext_vector_type(4))) float;

__device__ __forceinline__ float bf2f(u16 u) {
    union { unsigned int i; float f; } v; v.i = ((unsigned int)u) << 16; return v.f;
}
__device__ __forceinline__ u16 f2bf(float f) {
    union { float f; unsigned int i; } v; v.f = f;
    unsigned int x = v.i;
    return (u16)((x + 0x7fffu + ((x >> 16) & 1u)) >> 16);
}
__device__ __forceinline__ float siluf(float x) { return x / (1.f + __expf(-x)); }
__device__ __forceinline__ float softplusf(float x) { return (x > 20.f) ? x : log1pf(__expf(x)); }

// ---------------- mega setup: weight cvt (3264 blk) + head transpose (512 blk)
//                  + embed+rmsnorm (2048 blk) ----------------
__global__ __launch_bounds__(256) void mega0_k(const float* __restrict__ in_w,
                                               const float* __restrict__ xp_w,
                                               const float* __restrict__ dtp_w,
                                               const float* __restrict__ out_w,
                                               u16* __restrict__ w_in, u16* __restrict__ w_xp,
                                               u16* __restrict__ w_dt, u16* __restrict__ w_out,
                                               const float* __restrict__ head_w,
                                               u16* __restrict__ w_hd,
                                               const int* __restrict__ codes,
                                               const float* __restrict__ ew,
                                               const float* __restrict__ nw,
                                               float* __restrict__ x,
                                               u16* __restrict__ xn) {
    __shared__ float tile[64][65];
    int bid = blockIdx.x;
    int tid = threadIdx.x;
    if (bid < 3264) {
        // flat f32->bf16: in_w (2097152) | xp_w (131072) | dtp_w (65536) | out_w (1048576)
        int i = (bid * 256 + tid) << 2;
        const float* s; u16* d;
        if (i < 2097152) { s = in_w + i; d = w_in + i; }
        else {
            i -= 2097152;
            if (i < 131072) { s = xp_w + i; d = w_xp + i; }
            else {
                i -= 131072;
                if (i < 65536) { s = dtp_w + i; d = w_dt + i; }
                else { i -= 65536; s = out_w + i; d = w_out + i; }
            }
        }
        float4 v = *(const float4*)s;
        ushort4 o; o.x = f2bf(v.x); o.y = f2bf(v.y); o.z = f2bf(v.z); o.w = f2bf(v.w);
        *(ushort4*)d = o;
    } else if (bid < 3776) {
        // head transpose: w[4][512][1024] f32 -> wt[4][1024][512] bf16
        int idx = bid - 3264;
        int z = idx >> 7, rest = idx & 127;
        int d0 = (rest >> 4) << 6, v0 = (rest & 15) << 6;
        int col = tid & 63, rbase = tid >> 6;
#pragma unroll
        for (int i = 0; i < 16; i++) {
            int row = (i << 2) + rbase;
            tile[row][col] = head_w[(ll)z * (DM * V_SZ) + (ll)(d0 + row) * V_SZ + v0 + col];
        }
        __syncthreads();
#pragma unroll
        for (int i = 0; i < 16; i++) {
            int vrow = (i << 2) + rbase;
            w_hd[(ll)z * (V_SZ * DM) + (ll)(v0 + vrow) * DM + d0 + col] = f2bf(tile[col][vrow]);
        }
    } else {
        // embedding + rmsnorm (layer-0 input)
        int row = bid - 3776;  // b*1024 + t
        int b = row >> 10, t = row & 1023;
        float a0 = 0.f, a1 = 0.f;
#pragma unroll
        for (int k = 0; k < K_CB; k++) {
            int c = codes[b * (K_CB * T_SZ) + k * T_SZ + t];
            a0 += ew[((ll)k * V_SZ + c) * DM + tid];
            a1 += ew[((ll)k * V_SZ + c) * DM + tid + 256];
        }
        x[(ll)row * DM + tid]       = a0;
        x[(ll)row * DM + tid + 256] = a1;
        float ss = a0 * a0 + a1 * a1;
#pragma unroll
        for (int off = 32; off > 0; off >>= 1) ss += __shfl_down(ss, off, 64);
        float* red = &tile[0][0];
        if ((tid & 63) == 0) red[tid >> 6] = ss;
        __syncthreads();
        float tot = red[0] + red[1] + red[2] + red[3];
        float scale = rsqrtf(tot * (1.0f / DM) + 1e-6f);
        xn[(ll)row * DM + tid]       = f2bf(a0 * scale * nw[tid]);
        xn[(ll)row * DM + tid + 256] = f2bf(a1 * scale * nw[tid + 256]);
    }
}

// ---------------- rmsnorm (layer 1): f32 in -> bf16 out ----------------
__global__ __launch_bounds__(256) void rmsnorm_k(const float* __restrict__ x,
                                                 const float* __restrict__ w,
                                                 u16* __restrict__ xn) {
    ll row = blockIdx.x;
    const float* xr = x + row * DM;
    int tid = threadIdx.x;
    float v0 = xr[tid], v1 = xr[tid + 256];
    float ss = v0 * v0 + v1 * v1;
#pragma unroll
    for (int off = 32; off > 0; off >>= 1) ss += __shfl_down(ss, off, 64);
    __shared__ float red[4];
    if ((tid & 63) == 0) red[tid >> 6] = ss;
    __syncthreads();
    float tot = red[0] + red[1] + red[2] + red[3];
    float scale = rsqrtf(tot * (1.0f / DM) + 1e-6f);
    xn[row * DM + tid]       = f2bf(v0 * scale * w[tid]);
    xn[row * DM + tid + 256] = f2bf(v1 * scale * w[tid + 256]);
}

// ---------------- 128x128 MFMA GEMM, reg-prefetch + dual-LDS pipeline ----------------
// C[M,N] = A[M,K](bf16) * W[N,K](bf16)^T.  4 waves 2x2 -> each wave 64x64 = 4x4 mfma.
// EP0: bf16 store Cb (in_proj).  EP4: head f32 scatter, N=4096 (z=n>>10, v=n&1023).
template <int EP>
__global__ __launch_bounds__(256) void mgemm2_k(const u16* __restrict__ A, int lda,
                                                const u16* __restrict__ W,
                                                float* __restrict__ C,
                                                u16* __restrict__ Cb, int ldcb, int K) {
    __shared__ u16 As[2][4096];   // [128][32] each
    __shared__ u16 Bs[2][4096];
    int tid = threadIdx.x;
    int wave = tid >> 6, lane = tid & 63;
    int q = lane >> 4, r = lane & 15;
    int m0 = blockIdx.y << 7, n0 = blockIdx.x << 7;
    int wm = (wave >> 1) << 6, wn = (wave & 1) << 6;
    int srow = tid >> 1, soff = (tid & 1) << 4;     // row 0..127, u16-offset 0/16
    const u16* Ap = A + (ll)(m0 + srow) * lda + soff;
    const u16* Wp = W + (ll)(n0 + srow) * K + soff;
    int sidx = (srow << 5) + soff;
    f32x4 acc[4][4];
#pragma unroll
    for (int i = 0; i < 4; i++)
#pragma unroll
        for (int j = 0; j < 4; j++) acc[i][j] = (f32x4){0.f, 0.f, 0.f, 0.f};

    uint4 ra0 = *(const uint4*)Ap,       ra1 = *(const uint4*)(Ap + 8);
    uint4 rb0 = *(const uint4*)Wp,       rb1 = *(const uint4*)(Wp + 8);
    *(uint4*)&As[0][sidx] = ra0; *(uint4*)&As[0][sidx + 8] = ra1;
    *(uint4*)&Bs[0][sidx] = rb0; *(uint4*)&Bs[0][sidx + 8] = rb1;
    __syncthreads();

    int p = 0;
    for (int k0 = 0; k0 < K; k0 += 32) {
        bool pf = (k0 + 32) < K;
        if (pf) {
            ra0 = *(const uint4*)(Ap + k0 + 32); ra1 = *(const uint4*)(Ap + k0 + 40);
            rb0 = *(const uint4*)(Wp + k0 + 32); rb1 = *(const uint4*)(Wp + k0 + 40);
        }
        short8 af[4], bfr[4];
#pragma unroll
        for (int i = 0; i < 4; i++) af[i]  = *(const short8*)&As[p][((wm + (i << 4) + r) << 5) + (q << 3)];
#pragma unroll
        for (int j = 0; j < 4; j++) bfr[j] = *(const short8*)&Bs[p][((wn + (j << 4) + r) << 5) + (q << 3)];
#pragma unroll
        for (int i = 0; i < 4; i++)
#pragma unroll
            for (int j = 0; j < 4; j++)
                acc[i][j] = __builtin_amdgcn_mfma_f32_16x16x32_bf16(af[i], bfr[j], acc[i][j], 0, 0, 0);
        if (pf) {
            *(uint4*)&As[p ^ 1][sidx] = ra0; *(uint4*)&As[p ^ 1][sidx + 8] = ra1;
            *(uint4*)&Bs[p ^ 1][sidx] = rb0; *(uint4*)&Bs[p ^ 1][sidx + 8] = rb1;
        }
        __syncthreads();
        p ^= 1;
    }

#pragma unroll
    for (int i = 0; i < 4; i++)
#pragma unroll
        for (int j = 0; j < 4; j++)
#pragma unroll
            for (int g = 0; g < 4; g++) {
                int m = m0 + wm + (i << 4) + (q << 2) + g;
                int n = n0 + wn + (j << 4) + r;
                float v = acc[i][j][g];
                if (EP == 0) {
                    Cb[(ll)m * ldcb + n] = f2bf(v);
                } else {
                    int z = n >> 10, vv = n & 1023;
                    int b = m >> 10, t = m & 1023;
                    C[((ll)(b * K_CB + z) * T_SZ + t) * V_SZ + vv] = v;
                }
            }
}

// ---------------- 64x64 MFMA GEMM, reg-prefetch + dual-LDS pipeline ----------------
// EP3: C += acc, Cb = bf16(C) (out_proj).
template <int EP>
__global__ __launch_bounds__(256) void mgemm_k(const u16* __restrict__ A, int lda,
                                               const u16* __restrict__ W,
                                               float* __restrict__ C, int ldc, int K,
                                               const float* __restrict__ bias,
                                               u16* __restrict__ Cb, int ldcb) {
    __shared__ u16 As[2][2048];   // [64][32] each
    __shared__ u16 Bs[2][2048];
    int tid = threadIdx.x;
    int m0 = blockIdx.y << 6, n0 = blockIdx.x << 6;
    int lane = tid & 63, wave = tid >> 6;
    int q = lane >> 4, r = lane & 15;
    int wm = (wave >> 1) << 5, wn = (wave & 1) << 5;
    int srow = tid >> 2, soff = (tid & 3) << 3;     // row 0..63, u16-offset 0/8/16/24
    const u16* Ap = A + (ll)(m0 + srow) * lda + soff;
    const u16* Wp = W + (ll)(n0 + srow) * K + soff;
    int sidx = (srow << 5) + soff;
    f32x4 acc[2][2];
#pragma unroll
    for (int i = 0; i < 2; i++)
#pragma unroll
        for (int j = 0; j < 2; j++) acc[i][j] = (f32x4){0.f, 0.f, 0.f, 0.f};

    uint4 ra = *(const uint4*)Ap;
    uint4 rb = *(const uint4*)Wp;
    *(uint4*)&As[0][sidx] = ra;
    *(uint4*)&Bs[0][sidx] = rb;
    __syncthreads();

    int p = 0;
    for (int k0 = 0; k0 < K; k0 += 32) {
        bool pf = (k0 + 32) < K;
        if (pf) {
            ra = *(const uint4*)(Ap + k0 + 32);
            rb = *(const uint4*)(Wp + k0 + 32);
        }
        short8 af[2], bfr[2];
#pragma unroll
        for (int i = 0; i < 2; i++) af[i]  = *(const short8*)&As[p][((wm + (i << 4) + r) << 5) + (q << 3)];
#pragma unroll
        for (int j = 0; j < 2; j++) bfr[j] = *(const short8*)&Bs[p][((wn + (j << 4) + r) << 5) + (q << 3)];
#pragma unroll
        for (int i = 0; i < 2; i++)
#pragma unroll
            for (int j = 0; j < 2; j++)
                acc[i][j] = __builtin_amdgcn_mfma_f32_16x16x32_bf16(af[i], bfr[j], acc[i][j], 0, 0, 0);
        if (pf) {
            *(uint4*)&As[p ^ 1][sidx] = ra;
            *(uint4*)&Bs[p ^ 1][sidx] = rb;
        }
        __syncthreads();
        p ^= 1;
    }

#pragma unroll
    for (int i = 0; i < 2; i++)
#pragma unroll
        for (int j = 0; j < 2; j++)
#pragma unroll
            for (int g = 0; g < 4; g++) {
                int m = m0 + wm + (i << 4) + (q << 2) + g;
                int n = n0 + wn + (j << 4) + r;
                float v = acc[i][j][g];
                float nv = C[(ll)m * ldc + n] + v;
                C[(ll)m * ldc + n] = nv;
                Cb[(ll)m * ldcb + n] = f2bf(nv);
            }
}

// ---------------- fused causal dwconv(4)+silu + x_proj GEMM ----------------
// grid 128 = B * 64 row-groups; block owns 16 t-rows.
__global__ __launch_bounds__(256) void convxp_k(const u16* __restrict__ xzb,
                                                const float* __restrict__ cw,
                                                const float* __restrict__ cb,
                                                const u16* __restrict__ W,
                                                float* __restrict__ xc,
                                                float* __restrict__ xdbl,
                                                u16* __restrict__ xdbl_bf) {
    __shared__ u16 xcs[16][1032];   // bf16 xc tile, padded stride (16B pad)
    __shared__ u16 Bs[2][2048];     // [64][32] dbuf for W
    int blk = blockIdx.x, tid = threadIdx.x;
    int b = blk >> 6, tg = blk & 63;
    int t0 = tg << 4;
    ll ro0 = (ll)b * T_SZ + t0;
    int c0 = tid << 2;
    // conv weights + bias
    float4 a = *(const float4*)&cb[c0];
    float4 cwv[4];
#pragma unroll
    for (int e = 0; e < 4; e++) cwv[e] = *(const float4*)&cw[(c0 + e) << 2];
    // input rows t0-3 .. t0+15 for this thread's 4 channels
    ushort4 v[19];
#pragma unroll
    for (int i = 0; i < 19; i++) {
        int t = t0 - 3 + i;
        if (t >= 0) v[i] = *(const ushort4*)&xzb[((ll)(b * T_SZ + t)) * (2 * DI) + c0];
        else        v[i] = (ushort4){0, 0, 0, 0};
    }
#pragma unroll
    for (int tr = 0; tr < 16; tr++) {
        float acc0 = a.x, acc1 = a.y, acc2 = a.z, acc3 = a.w;
#pragma unroll
        for (int j = 0; j < 4; j++) {
            ushort4 vv = v[tr + j];
            acc0 = fmaf(bf2f(vv.x), ((const float*)&cwv[0])[j], acc0);
            acc1 = fmaf(bf2f(vv.y), ((const float*)&cwv[1])[j], acc1);
            acc2 = fmaf(bf2f(vv.z), ((const float*)&cwv[2])[j], acc2);
            acc3 = fmaf(bf2f(vv.w), ((const float*)&cwv[3])[j], acc3);
        }
        float4 s; ushort4 sb;
        s.x = siluf(acc0); s.y = siluf(acc1); s.z = siluf(acc2); s.w = siluf(acc3);
        sb.x = f2bf(s.x); sb.y = f2bf(s.y); sb.z = f2bf(s.z); sb.w = f2bf(s.w);
        *(float4*)&xc[(ro0 + tr) * DI + c0] = s;
        *(ushort4*)&xcs[tr][c0] = sb;
    }
    __syncthreads();

    // Phase 2: MFMA x_dbl = xcs(16x1024) @ W(64x1024)^T
    int lane = tid & 63, wave = tid >> 6;
    int q = lane >> 4, r = lane & 15;
    int srow = tid >> 2, soff = (tid & 3) << 3;
    f32x4 acc = (f32x4){0.f, 0.f, 0.f, 0.f};
    uint4 rb = *(const uint4*)(W + (ll)srow * DI + soff);
    *(uint4*)&Bs[0][(srow << 5) + soff] = rb;
    __syncthreads();
    int p = 0;
    for (int k0 = 0; k0 < DI; k0 += 32) {
        bool pf = (k0 + 32) < DI;
        if (pf) rb = *(const uint4*)(W + (ll)srow * DI + k0 + 32 + soff);
        short8 af  = *(const short8*)&xcs[r][k0 + (q << 3)];
        short8 bfr = *(const short8*)&Bs[p][(((wave << 4) + r) << 5) + (q << 3)];
        acc = __builtin_amdgcn_mfma_f32_16x16x32_bf16(af, bfr, acc, 0, 0, 0);
        if (pf) *(uint4*)&Bs[p ^ 1][(srow << 5) + soff] = rb;
        __syncthreads();
        p ^= 1;
    }
    // C/D layout: row = q*4+g (t within tile), col = r; wave's col base = wave*16
#pragma unroll
    for (int g = 0; g < 4; g++) {
        int tr = (q << 2) + g;
        int n = (wave << 4) + r;
        float vv = acc[g];
        xdbl[(ro0 + tr) * 64 + n]    = vv;
        xdbl_bf[(ro0 + tr) * 64 + n] = f2bf(vv);
    }
}

// ---------------- fused dt_proj GEMM + scan pass 1 ----------------
// grid dim3(16,32) = 512 blocks; tile 64(t) x 64(d).
// pA/U layout: [b][c][n][d] (d innermost) -> dense 256B stores per instruction.
__global__ __launch_bounds__(256) void dtscan1_k(const u16* __restrict__ A,
                                                 const u16* __restrict__ W,
                                                 const float* __restrict__ bias,
                                                 const float* __restrict__ xc,
                                                 const float* __restrict__ xdbl,
                                                 const float* __restrict__ A_log,
                                                 float* __restrict__ dtb,
                                                 float* __restrict__ pA,
                                                 float* __restrict__ U) {
    __shared__ u16 As[2048];        // [64][32]
    __shared__ u16 Bs[2048];
    __shared__ float dts[64][65];   // padded
    __shared__ float BCs[64][16];   // B part of x_dbl for the block's 64 rows
    int tid = threadIdx.x;
    int m0 = blockIdx.y << 6, n0 = blockIdx.x << 6;
    int lane = tid & 63, wave = tid >> 6;
    int q = lane >> 4, r = lane & 15;
    int wm = (wave >> 1) << 5, wn = (wave & 1) << 5;
    {   // stage A (xdbl_bf rows m0.., k=0..31) and B (w_dt rows n0.., k=0..31)
        int srow = tid >> 2, soff = (tid & 3) << 3;
        *(uint4*)&As[(srow << 5) + soff] = *(const uint4*)(A + (ll)(m0 + srow) * 64 + soff);
        *(uint4*)&Bs[(srow << 5) + soff] = *(const uint4*)(W + (ll)(n0 + srow) * DTR + soff);
        // stage B-coefficients for scan: xdbl[row][32..47], 64 rows x 16 f32
        int rr = tid >> 2, cc = (tid & 3) << 2;
        *(float4*)&BCs[rr][cc] = *(const float4*)&xdbl[(ll)(m0 + rr) * 64 + DTR + cc];
    }
    // per-thread scan constants (independent of LDS)
    int sd = lane;             // d offset within tile (scan mapping)
    int sc = wave;             // chunk 0..3 within tile
    int dg = n0 + sd;
    float Av[NS];
#pragma unroll
    for (int n4 = 0; n4 < 4; n4++) {
        float4 alv = *(const float4*)&A_log[dg * NS + (n4 << 2)];
        Av[(n4 << 2) + 0] = -__expf(alv.x); Av[(n4 << 2) + 1] = -__expf(alv.y);
        Av[(n4 << 2) + 2] = -__expf(alv.z); Av[(n4 << 2) + 3] = -__expf(alv.w);
    }
    __syncthreads();

    // GEMM: one K=32 step
    f32x4 acc[2][2];
#pragma unroll
    for (int i = 0; i < 2; i++)
#pragma unroll
        for (int j = 0; j < 2; j++) acc[i][j] = (f32x4){0.f, 0.f, 0.f, 0.f};
    short8 af[2], bfr[2];
#pragma unroll
    for (int i = 0; i < 2; i++) af[i]  = *(const short8*)&As[((wm + (i << 4) + r) << 5) + (q << 3)];
#pragma unroll
    for (int j = 0; j < 2; j++) bfr[j] = *(const short8*)&Bs[((wn + (j << 4) + r) << 5) + (q << 3)];
#pragma unroll
    for (int i = 0; i < 2; i++)
#pragma unroll
        for (int j = 0; j < 2; j++)
            acc[i][j] = __builtin_amdgcn_mfma_f32_16x16x32_bf16(af[i], bfr[j], acc[i][j], 0, 0, 0);

    // epilogue: softplus(+bias) -> dtb global + dts LDS
#pragma unroll
    for (int i = 0; i < 2; i++)
#pragma unroll
        for (int j = 0; j < 2; j++)
#pragma unroll
            for (int g = 0; g < 4; g++) {
                int mm = wm + (i << 4) + (q << 2) + g;
                int nn = wn + (j << 4) + r;
                float dtl = softplusf(acc[i][j][g] + bias[n0 + nn]);
                dtb[(ll)(m0 + mm) * DI + (n0 + nn)] = dtl;
                dts[mm][nn] = dtl;
            }
    __syncthreads();

    // scan pass 1: thread (sc, sd) runs chunk c over its 16 steps
    int b = m0 >> 10;
    int c = ((m0 & 1023) >> 4) + sc;
    int tl0 = sc << 4;
    float p[NS], u[NS];
#pragma unroll
    for (int n = 0; n < NS; n++) { p[n] = 1.f; u[n] = 0.f; }
#pragma unroll
    for (int s = 0; s < TCHUNK; s++) {
        int tl = tl0 + s;
        float dtv = dts[tl][sd];
        float xv = xc[(ll)(m0 + tl) * DI + dg];
        float dx = dtv * xv;
#pragma unroll
        for (int n = 0; n < NS; n++) {
            float aa = __expf(dtv * Av[n]);
            p[n] *= aa;
            u[n] = fmaf(aa, u[n], dx * BCs[tl][n]);
        }
    }
    // store: [b][c][n][d] layout -> lane-consecutive d = dense 256B per instr
    ll o = ((ll)b * NCHUNK + c) * (NS * DI) + dg;
#pragma unroll
    for (int n = 0; n < NS; n++) { pA[o + n * DI] = p[n]; U[o + n * DI] = u[n]; }
}

// pass 2: combine over chunks; hst aliases U (read U before write).
// Layout-agnostic: rest indexes the per-(b,c) slab of 16384 elems (now n*DI+d).
__global__ __launch_bounds__(256) void scan2_k(const float* __restrict__ pA,
                                               const float* __restrict__ U,
                                               float* __restrict__ hst) {
    int i = blockIdx.x * 256 + threadIdx.x;  // b*(NS*DI) + n*DI + d
    int b = i >> 14;
    int rest = i & 16383;
    float h = 0.f;
#pragma unroll
    for (int c = 0; c < NCHUNK; c++) {
        ll o = ((ll)b * NCHUNK + c) * (DI * NS) + rest;
        float pa = pA[o], u = U[o];
        hst[o] = h;
        h = fmaf(pa, h, u);
    }
}

// pass 3: replay with true initial h; fuse D_skip + silu(z) gate; bf16 y out.
// hst read in [b][c][n][d] layout -> lane-consecutive d = dense loads.
__global__ __launch_bounds__(256) void scan3_k(const float* __restrict__ dt,
                                               const float* __restrict__ xc,
                                               const float* __restrict__ xdbl,
                                               const u16* __restrict__ xzb,
                                               const float* __restrict__ A_log,
                                               const float* __restrict__ Dk,
                                               const float* __restrict__ hst,
                                               u16* __restrict__ y) {
    int blk = blockIdx.x;
    int dblk = blk & 3;
    int c = (blk >> 2) & (NCHUNK - 1);
    int b = blk >> 8;
    int d = dblk * 256 + threadIdx.x;
    int t0 = c * TCHUNK;
    __shared__ float BC[TCHUNK][32];
    if (threadIdx.x < TCHUNK * 8) {
        int rr = threadIdx.x >> 3, cc = (threadIdx.x & 7) << 2;
        *(float4*)&BC[rr][cc] = *(const float4*)&xdbl[((ll)(b * T_SZ + t0 + rr)) * 64 + DTR + cc];
    }
    float Av[NS];
#pragma unroll
    for (int n4 = 0; n4 < 4; n4++) {
        float4 alv = *(const float4*)&A_log[d * NS + (n4 << 2)];
        Av[(n4 << 2) + 0] = -__expf(alv.x); Av[(n4 << 2) + 1] = -__expf(alv.y);
        Av[(n4 << 2) + 2] = -__expf(alv.z); Av[(n4 << 2) + 3] = -__expf(alv.w);
    }
    float h[NS];
    ll ho = (((ll)b * NCHUNK + c) * (NS * DI)) + d;
#pragma unroll
    for (int n = 0; n < NS; n++) h[n] = hst[ho + n * DI];
    float Dv = Dk[d];
    __syncthreads();
#pragma unroll
    for (int s = 0; s < TCHUNK; s++) {
        ll ro = (ll)(b * T_SZ + t0 + s);
        float dtv = dt[ro * DI + d];
        float xv = xc[ro * DI + d];
        float dx = dtv * xv;
        float acc = 0.f;
#pragma unroll
        for (int n = 0; n < NS; n++) {
            float aa = __expf(dtv * Av[n]);
            h[n] = fmaf(aa, h[n], dx * BC[s][n]);
            acc = fmaf(h[n], BC[s][16 + n], acc);
        }
        float zv = bf2f(xzb[ro * (2 * DI) + DI + d]);
        y[ro * DI + d] = f2bf((acc + xv * Dv) * siluf(zv));
    }
}

extern "C" void kernel_launch(void* const* d_in, const int* in_sizes, int n_in,
                              void* d_out, int out_size, void* d_ws, size_t ws_size,
                              hipStream_t stream) {
    const int*   codes   = (const int*)d_in[0];
    const float* embed_w = (const float*)d_in[1];
    const float* norm_w  = (const float*)d_in[2];
    const float* in_w    = (const float*)d_in[3];
    const float* conv_w  = (const float*)d_in[4];
    const float* conv_b  = (const float*)d_in[5];
    const float* xp_w    = (const float*)d_in[6];
    const float* dtp_w   = (const float*)d_in[7];
    const float* dtp_b   = (const float*)d_in[8];
    const float* A_log   = (const float*)d_in[9];
    const float* D_skip  = (const float*)d_in[10];
    const float* out_w   = (const float*)d_in[11];
    const float* head_w  = (const float*)d_in[12];
    float* out = (float*)d_out;

    float* ws = (float*)d_ws;
    float* x    = ws;                  // 1,048,576 f32
    float* xc   = x + 1048576;         // 2,097,152
    float* dtb  = xc + 2097152;        // 2,097,152
    float* xdbl = dtb + 2097152;       // 131,072
    float* pA   = xdbl + 131072;       // 2,097,152
    float* Uh   = pA + 2097152;        // 2,097,152 (U, then hst in-place)

    u16* us       = (u16*)(Uh + 2097152);
    u16* xz_bf    = us;                 // 4,194,304
    u16* xbf      = xz_bf + 4194304;    // 2,097,152 (x_bf: bf16 of residual x)
    u16* ybxn_bf  = xbf + 2097152;      // 2,097,152 (y_bf full; xn_bf shares first 1M)
    u16* xdbl_bf  = ybxn_bf + 2097152;  // 131,072
    u16* w_in_bf  = xdbl_bf + 131072;   // 2,097,152
    u16* w_xp_bf  = w_in_bf + 2097152;  // 131,072
    u16* w_dt_bf  = w_xp_bf + 131072;   // 65,536
    u16* w_out_bf = w_dt_bf + 65536;    // 1,048,576
    u16* w_hd_bf  = w_out_bf + 1048576; // 2,097,152 ([4096][512])

    u16* xn_bf = ybxn_bf;
    u16* y_bf  = ybxn_bf;
    u16* x_bf  = xbf;

    // setup: weight conversions + head transpose + embed/rmsnorm, one dispatch
    mega0_k<<<5824, 256, 0, stream>>>(in_w, xp_w, dtp_w, out_w,
                                      w_in_bf, w_xp_bf, w_dt_bf, w_out_bf,
                                      head_w, w_hd_bf, codes, embed_w, norm_w, x, xn_bf);

    for (int l = 0; l < 2; l++) {
        const float* al = A_log + l * DI * NS;
        if (l == 1)
            rmsnorm_k<<<2048, 256, 0, stream>>>(x, norm_w + DM, xn_bf);
        // xz = xn @ in_w^T : (2048 x 2048), K=512 -> bf16.  128x128 tiles, 256 blocks
        mgemm2_k<0><<<dim3(16, 16), 256, 0, stream>>>(xn_bf, DM, w_in_bf + l * 1048576,
                                                      nullptr, xz_bf, 2 * DI, DM);
        // fused conv + x_proj: 128 blocks
        convxp_k<<<128, 256, 0, stream>>>(xz_bf, conv_w + l * DI * 4, conv_b + l * DI,
                                          w_xp_bf + l * 65536, xc, xdbl, xdbl_bf);
        // fused dt_proj + scan pass 1: 512 blocks
        dtscan1_k<<<dim3(16, 32), 256, 0, stream>>>(xdbl_bf, w_dt_bf + l * 32768,
                                                    dtp_b + l * DI, xc, xdbl, al,
                                                    dtb, pA, Uh);
        scan2_k<<<128, 256, 0, stream>>>(pA, Uh, Uh);
        scan3_k<<<512, 256, 0, stream>>>(dtb, xc, xdbl, xz_bf, al, D_skip + l * DI, Uh, y_bf);
        // x += y @ out_w^T : (2048 x 512), K=1024; also x_bf = bf16(x)
        mgemm_k<3><<<dim3(8, 32), 256, 0, stream>>>(y_bf, DI, w_out_bf + l * 524288,
                                                    x, DM, DI, nullptr, x_bf, DM);
    }

    // head: single GEMM M=2048 x N=4096 x K=512, 128x128 tiles, 512 blocks = 2 blk/CU
    mgemm2_k<4><<<dim3(32, 16), 256, 0, stream>>>(x_bf, DM, w_hd_bf, out, nullptr, 0, DM);
}